// Round 9
// baseline (360.269 us; speedup 1.0000x reference)
//
#include <hip/hip_runtime.h>
#include <hip/hip_bf16.h>
#include <cstdint>

#define B_SZ   512
#define NLAT   64
#define H_SZ   32
#define G_OI_N 5000
#define K_SZ   64

#define BT_GROUPS 16   // b-tiles of 32 rows
#define CHUNKS    50   // gene chunks per b-tile
#define GPC       100  // genes per chunk (50*100 = 5000)

typedef __attribute__((ext_vector_type(8))) short short8v;   // 8 x bf16
typedef __attribute__((ext_vector_type(4))) float float4v;

__device__ __forceinline__ unsigned short f2bf(float x) {
    union { float f; unsigned u; } v; v.f = x;
    unsigned r = v.u + 0x7fff + ((v.u >> 16) & 1);            // RTNE
    return (unsigned short)(r >> 16);
}

// ---------------- Kernel A: h = BN(relu(latent @ W1 + b1))
// writes fp32 h (for rho) and bf16 h (for logit MFMA operand)
__global__ __launch_bounds__(256) void mlp_kernel(
    const float* __restrict__ latent, const float* __restrict__ W1,
    const float* __restrict__ b1, const float* __restrict__ gamma,
    const float* __restrict__ beta, const float* __restrict__ mean,
    const float* __restrict__ var, float* __restrict__ hout,
    unsigned short* __restrict__ hbf)
{
    int idx = blockIdx.x * 256 + threadIdx.x;   // 0..16383 = b*32 + j
    int b = idx >> 5;
    int j = idx & 31;
    float acc = 0.f;
    const float4* lp = reinterpret_cast<const float4*>(latent + b * NLAT);
#pragma unroll
    for (int q = 0; q < NLAT / 4; ++q) {
        float4 lv = lp[q];
        acc = fmaf(lv.x, W1[(4 * q + 0) * H_SZ + j], acc);
        acc = fmaf(lv.y, W1[(4 * q + 1) * H_SZ + j], acc);
        acc = fmaf(lv.z, W1[(4 * q + 2) * H_SZ + j], acc);
        acc = fmaf(lv.w, W1[(4 * q + 3) * H_SZ + j], acc);
    }
    acc += b1[j];
    acc = fmaxf(acc, 0.f);
    acc = gamma[j] * (acc - mean[j]) * rsqrtf(var[j] + 1e-5f) + beta[j];
    hout[idx] = acc;
    hbf[idx]  = f2bf(acc);
}

// ---------------- Kernel B (MFMA, b-major / gene-streaming):
// Block = 32 b-rows (2 m-tiles) x 100 consecutive genes; wave = one k-tile.
// Swapped operands: A = lw^T tile (16 kcols x 32 h), B = h^T tile (32 h x 16 b)
//   => D: col(lane&15) = b, row((lane>>4)*4+r) = k  -> dwordx4 stores of
//   consecutive k. Per gene the block writes out[b, g, 0:64] complete for its
//   32 rows => each b-row is a sequential DRAM stream advancing 256B/gene.
// (Both fragment address patterns HW-verified in round 8.)
__global__ __launch_bounds__(256) void logit_kernel(
    const unsigned short* __restrict__ hbf, const int* __restrict__ genes,
    const float* __restrict__ lw, float* __restrict__ out)
{
    const int chunk = blockIdx.x % CHUNKS;
    const int bt    = blockIdx.x / CHUNKS;     // 0..15
    const int lane  = threadIdx.x & 63;
    const int kt    = threadIdx.x >> 6;        // wave = k-tile 0..3
    const int row16 = lane & 15;
    const int kg    = lane >> 4;               // 0..3

    // B operand (h^T) for the 2 m-tiles, loaded once, reused over 100 genes.
    short8v bfr[2];
#pragma unroll
    for (int mt = 0; mt < 2; ++mt)
        bfr[mt] = *reinterpret_cast<const short8v*>(
            hbf + (bt * 32 + mt * 16 + row16) * H_SZ + kg * 8);

    const size_t GK = (size_t)G_OI_N * K_SZ;
    const int g0 = chunk * GPC;
#pragma unroll 2
    for (int i = 0; i < GPC; ++i) {
        const int g = g0 + i;
        const size_t gene = (size_t)genes[g];
        // A fragment: lw[gene, kg*8+j, kt*16 + row16], j=0..7
        const float* ap = lw + gene * (size_t)(H_SZ * K_SZ)
                             + (size_t)(kg * 8) * K_SZ + kt * 16 + row16;
        short8v afr;
#pragma unroll
        for (int j = 0; j < 8; ++j)
            afr[j] = (short)f2bf(ap[(size_t)j * K_SZ]);

        float* og = out + (size_t)g * K_SZ + kt * 16 + kg * 4;
#pragma unroll
        for (int mt = 0; mt < 2; ++mt) {
            float4v acc = {0.f, 0.f, 0.f, 0.f};
            acc = __builtin_amdgcn_mfma_f32_16x16x32_bf16(afr, bfr[mt], acc, 0, 0, 0);
            *reinterpret_cast<float4v*>(
                og + (size_t)(bt * 32 + mt * 16 + row16) * GK) = acc;
        }
    }
}

// ---------------- Kernel C: rho[b,g] = sum_h h[b,h] * rw[genes[g],h]
__global__ __launch_bounds__(256) void rho_kernel(
    const float* __restrict__ hbuf, const int* __restrict__ genes,
    const float* __restrict__ rw, float* __restrict__ out)
{
    const int gx = blockIdx.x % 20;
    const int bx = blockIdx.x / 20;
    const int g = gx * 256 + threadIdx.x;
    if (g >= G_OI_N) return;
    const size_t gene = (size_t)genes[g];

    float rreg[H_SZ];
    const float4* rp = reinterpret_cast<const float4*>(rw + gene * H_SZ);
#pragma unroll
    for (int q = 0; q < 8; ++q) {
        float4 rv = rp[q];
        rreg[4 * q + 0] = rv.x; rreg[4 * q + 1] = rv.y;
        rreg[4 * q + 2] = rv.z; rreg[4 * q + 3] = rv.w;
    }

    const int b0 = bx * 32;
    for (int b = b0; b < b0 + 32; ++b) {
        const float4* hp = reinterpret_cast<const float4*>(hbuf + b * H_SZ);
        float a0 = 0.f, a1 = 0.f, a2 = 0.f, a3 = 0.f;
#pragma unroll
        for (int q = 0; q < 8; ++q) {
            float4 hv = hp[q];
            a0 = fmaf(hv.x, rreg[4 * q + 0], a0);
            a1 = fmaf(hv.y, rreg[4 * q + 1], a1);
            a2 = fmaf(hv.z, rreg[4 * q + 2], a2);
            a3 = fmaf(hv.w, rreg[4 * q + 3], a3);
        }
        out[(size_t)b * G_OI_N + g] = (a0 + a1) + (a2 + a3);
    }
}

extern "C" void kernel_launch(void* const* d_in, const int* in_sizes, int n_in,
                              void* d_out, int out_size, void* d_ws, size_t ws_size,
                              hipStream_t stream)
{
    // Bind inputs by SIZE SIGNATURE (all sizes unique; robust to ordering).
    const float *latent = nullptr, *W1 = nullptr, *lw = nullptr, *rw = nullptr;
    const int* genes = nullptr;
    const float* small[5] = {nullptr, nullptr, nullptr, nullptr, nullptr};
    int nsmall = 0;
    for (int i = 0; i < n_in; ++i) {
        switch (in_sizes[i]) {
            case 32768:    latent = (const float*)d_in[i]; break;
            case 5000:
            case 10000:    genes  = (const int*)d_in[i];   break;
            case 2048:     W1     = (const float*)d_in[i]; break;
            case 40960000: lw     = (const float*)d_in[i]; break;
            case 640000:   rw     = (const float*)d_in[i]; break;
            case 32: if (nsmall < 5) small[nsmall++] = (const float*)d_in[i]; break;
            default: break;
        }
    }
    if (!latent || !genes || !W1 || !lw || !rw || nsmall < 5) return;
    const float* b1v   = small[0];
    const float* gamma = small[1];
    const float* beta  = small[2];
    const float* mean  = small[3];
    const float* var   = small[4];

    float* hbuf = (float*)d_ws;                                    // 64 KB fp32 h
    unsigned short* hbf = (unsigned short*)((char*)d_ws + 65536);  // 32 KB bf16 h
    float* logit_out = (float*)d_out;                              // [512,5000,64]
    float* rho_out   = logit_out + (size_t)B_SZ * G_OI_N * K_SZ;   // [512,5000]

    mlp_kernel<<<(B_SZ * H_SZ) / 256, 256, 0, stream>>>(latent, W1, b1v, gamma, beta,
                                                        mean, var, hbuf, hbf);
    logit_kernel<<<BT_GROUPS * CHUNKS, 256, 0, stream>>>(hbf, genes, lw, logit_out);
    rho_kernel<<<20 * 16, 256, 0, stream>>>(hbuf, genes, rw, rho_out);
}

// Round 10
// 178.631 us; speedup vs baseline: 2.0168x; 2.0168x over previous
//
#include <hip/hip_runtime.h>
#include <hip/hip_bf16.h>
#include <cstdint>

#define B_SZ   512
#define NLAT   64
#define H_SZ   32
#define G_OI_N 5000
#define K_SZ   64

#define GPC    8      // genes per chunk
#define NCHUNK 625    // 625*8 = 5000

typedef __attribute__((ext_vector_type(8))) short short8v;   // 8 x bf16
typedef __attribute__((ext_vector_type(4))) float float4v;

__device__ __forceinline__ unsigned short f2bf(float x) {
    union { float f; unsigned u; } v; v.f = x;
    unsigned r = v.u + 0x7fff + ((v.u >> 16) & 1);            // RTNE
    return (unsigned short)(r >> 16);
}

// ---------------- Kernel A: h = BN(relu(latent @ W1 + b1))
// writes fp32 h (for rho) and bf16 h (for logit MFMA operand)
__global__ __launch_bounds__(256) void mlp_kernel(
    const float* __restrict__ latent, const float* __restrict__ W1,
    const float* __restrict__ b1, const float* __restrict__ gamma,
    const float* __restrict__ beta, const float* __restrict__ mean,
    const float* __restrict__ var, float* __restrict__ hout,
    unsigned short* __restrict__ hbf)
{
    int idx = blockIdx.x * 256 + threadIdx.x;   // 0..16383 = b*32 + j
    int b = idx >> 5;
    int j = idx & 31;
    float acc = 0.f;
    const float4* lp = reinterpret_cast<const float4*>(latent + b * NLAT);
#pragma unroll
    for (int q = 0; q < NLAT / 4; ++q) {
        float4 lv = lp[q];
        acc = fmaf(lv.x, W1[(4 * q + 0) * H_SZ + j], acc);
        acc = fmaf(lv.y, W1[(4 * q + 1) * H_SZ + j], acc);
        acc = fmaf(lv.z, W1[(4 * q + 2) * H_SZ + j], acc);
        acc = fmaf(lv.w, W1[(4 * q + 3) * H_SZ + j], acc);
    }
    acc += b1[j];
    acc = fmaxf(acc, 0.f);
    acc = gamma[j] * (acc - mean[j]) * rsqrtf(var[j] + 1e-5f) + beta[j];
    hout[idx] = acc;
    hbf[idx]  = f2bf(acc);
}

// ---------------- Kernel B v3 (MFMA, write-stream-optimized):
// Block = 4 waves (wave = k-tile kt) x 256 b-rows x 8 consecutive genes.
// All operands in VGPRs: hfr[16] (h^T B-operand, 64 VGPR), afr[8] (lw A-operand,
// loaded ONCE per block -> r9's 16x re-gather removed). Loop mt outer / gi
// inner: each 16-row group gets 8 genes x 256 B = 2 KB/row co-temporal, visited
// once per block -> fill-kernel-like DRAM streams (~5k streams, 1250 blocks).
// Fragment patterns + D layout (col=b, row=k -> dwordx4 of consecutive k) are
// HW-verified by rounds 8/9.
__global__ __launch_bounds__(256) void logit_kernel(
    const unsigned short* __restrict__ hbf, const int* __restrict__ genes,
    const float* __restrict__ lw, float* __restrict__ out)
{
    const int bh    = blockIdx.x & 1;          // b-half: 256 rows
    const int chunk = blockIdx.x >> 1;         // 0..624
    const int lane  = threadIdx.x & 63;
    const int kt    = threadIdx.x >> 6;        // wave = k-tile 0..3
    const int row16 = lane & 15;
    const int kg    = lane >> 4;               // 0..3
    const int b0    = bh * 256;

    // h fragments (B-operand): rows b0..b0+255, loaded once, reused 8 genes.
    short8v hfr[16];
#pragma unroll
    for (int mt = 0; mt < 16; ++mt)
        hfr[mt] = *reinterpret_cast<const short8v*>(
            hbf + (b0 + mt * 16 + row16) * H_SZ + kg * 8);

    // lw fragments (A-operand) for 8 consecutive genes, once per block.
    const int g0 = chunk * GPC;
    short8v afr[GPC];
#pragma unroll
    for (int gi = 0; gi < GPC; ++gi) {
        const size_t gene = (size_t)genes[g0 + gi];
        const float* ap = lw + gene * (size_t)(H_SZ * K_SZ)
                             + (size_t)(kg * 8) * K_SZ + kt * 16 + row16;
#pragma unroll
        for (int j = 0; j < 8; ++j)
            afr[gi][j] = (short)f2bf(ap[(size_t)j * K_SZ]);
    }

    const size_t GK = (size_t)G_OI_N * K_SZ;
    float* orow = out + (size_t)g0 * K_SZ + kt * 16 + kg * 4;
    for (int mt = 0; mt < 16; ++mt) {
        float* obase = orow + (size_t)(b0 + mt * 16 + row16) * GK;
#pragma unroll
        for (int gi = 0; gi < GPC; ++gi) {
            float4v acc = {0.f, 0.f, 0.f, 0.f};
            acc = __builtin_amdgcn_mfma_f32_16x16x32_bf16(afr[gi], hfr[mt], acc, 0, 0, 0);
            *reinterpret_cast<float4v*>(obase + (size_t)gi * K_SZ) = acc;
        }
    }
}

// ---------------- Kernel C: rho[b,g] = sum_h h[b,h] * rw[genes[g],h]
__global__ __launch_bounds__(256) void rho_kernel(
    const float* __restrict__ hbuf, const int* __restrict__ genes,
    const float* __restrict__ rw, float* __restrict__ out)
{
    const int gx = blockIdx.x % 20;
    const int bx = blockIdx.x / 20;
    const int g = gx * 256 + threadIdx.x;
    if (g >= G_OI_N) return;
    const size_t gene = (size_t)genes[g];

    float rreg[H_SZ];
    const float4* rp = reinterpret_cast<const float4*>(rw + gene * H_SZ);
#pragma unroll
    for (int q = 0; q < 8; ++q) {
        float4 rv = rp[q];
        rreg[4 * q + 0] = rv.x; rreg[4 * q + 1] = rv.y;
        rreg[4 * q + 2] = rv.z; rreg[4 * q + 3] = rv.w;
    }

    const int b0 = bx * 32;
    for (int b = b0; b < b0 + 32; ++b) {
        const float4* hp = reinterpret_cast<const float4*>(hbuf + b * H_SZ);
        float a0 = 0.f, a1 = 0.f, a2 = 0.f, a3 = 0.f;
#pragma unroll
        for (int q = 0; q < 8; ++q) {
            float4 hv = hp[q];
            a0 = fmaf(hv.x, rreg[4 * q + 0], a0);
            a1 = fmaf(hv.y, rreg[4 * q + 1], a1);
            a2 = fmaf(hv.z, rreg[4 * q + 2], a2);
            a3 = fmaf(hv.w, rreg[4 * q + 3], a3);
        }
        out[(size_t)b * G_OI_N + g] = (a0 + a1) + (a2 + a3);
    }
}

extern "C" void kernel_launch(void* const* d_in, const int* in_sizes, int n_in,
                              void* d_out, int out_size, void* d_ws, size_t ws_size,
                              hipStream_t stream)
{
    // Bind inputs by SIZE SIGNATURE (all sizes unique; robust to ordering).
    const float *latent = nullptr, *W1 = nullptr, *lw = nullptr, *rw = nullptr;
    const int* genes = nullptr;
    const float* small[5] = {nullptr, nullptr, nullptr, nullptr, nullptr};
    int nsmall = 0;
    for (int i = 0; i < n_in; ++i) {
        switch (in_sizes[i]) {
            case 32768:    latent = (const float*)d_in[i]; break;
            case 5000:
            case 10000:    genes  = (const int*)d_in[i];   break;
            case 2048:     W1     = (const float*)d_in[i]; break;
            case 40960000: lw     = (const float*)d_in[i]; break;
            case 640000:   rw     = (const float*)d_in[i]; break;
            case 32: if (nsmall < 5) small[nsmall++] = (const float*)d_in[i]; break;
            default: break;
        }
    }
    if (!latent || !genes || !W1 || !lw || !rw || nsmall < 5) return;
    const float* b1v   = small[0];
    const float* gamma = small[1];
    const float* beta  = small[2];
    const float* mean  = small[3];
    const float* var   = small[4];

    float* hbuf = (float*)d_ws;                                    // 64 KB fp32 h
    unsigned short* hbf = (unsigned short*)((char*)d_ws + 65536);  // 32 KB bf16 h
    float* logit_out = (float*)d_out;                              // [512,5000,64]
    float* rho_out   = logit_out + (size_t)B_SZ * G_OI_N * K_SZ;   // [512,5000]

    mlp_kernel<<<(B_SZ * H_SZ) / 256, 256, 0, stream>>>(latent, W1, b1v, gamma, beta,
                                                        mean, var, hbuf, hbf);
    logit_kernel<<<2 * NCHUNK, 256, 0, stream>>>(hbf, genes, lw, logit_out);
    rho_kernel<<<20 * 16, 256, 0, stream>>>(hbuf, genes, rw, rho_out);
}